// Round 10
// baseline (67.731 us; speedup 1.0000x reference)
//
#include <hip/hip_runtime.h>
#include <math.h>

typedef unsigned short u16;
typedef __attribute__((ext_vector_type(4))) float f32x4;
typedef __bf16 bf16x8 __attribute__((ext_vector_type(8)));

#define MFMA16(a,b,c) __builtin_amdgcn_mfma_f32_16x16x32_bf16((a),(b),(c),0,0,0)

typedef const __attribute__((address_space(1))) unsigned GU;
typedef __attribute__((address_space(3))) unsigned LU;
__device__ __forceinline__ void gl_lds16(const void* g, void* l) {
    // dest = wave-uniform LDS base + lane*16 ; src = per-lane global address
    __builtin_amdgcn_global_load_lds((GU*)g, (LU*)l, 16, 0, 0);
}

__device__ __forceinline__ u16 f2b(float f) {
    __bf16 h = (__bf16)f;             // RNE
    return __builtin_bit_cast(u16, h);
}
__device__ __forceinline__ float b2f(u16 u) {
    unsigned v = (unsigned)u << 16;
    return __builtin_bit_cast(float, v);
}

// ---------- 1. wtrans: W[1024][64] f32 x3 -> fragment-native Wt2 ----------
// Wt2 u16 [kstep=16][cg=12][kh=2][hl=2][kg=4][r=16][e=8]  (1KB frags, 768KB total)
__global__ __launch_bounds__(128) void wtrans_kernel(
    const float* __restrict__ Wq, const float* __restrict__ Wk,
    const float* __restrict__ Wv, u16* __restrict__ Wt2)
{
    const int n = blockIdx.x;                         // 0..191
    const float* W = (n < 64) ? Wq : ((n < 128) ? Wk : Wv);
    const int nc = n & 63, cg = n >> 4, r = n & 15;
    const int t = threadIdx.x;                        // 0..127
    const int k0 = t * 8;
    const int kstep = k0 >> 6, kh = (k0 >> 5) & 1, kg = (k0 >> 3) & 3;
    u16 hh[8], ll[8];
#pragma unroll
    for (int i = 0; i < 8; ++i) {
        const float a = W[(size_t)(k0 + i) * 64 + nc];
        hh[i] = f2b(a);
        ll[i] = f2b(a - b2f(hh[i]));
    }
    const size_t fi = (((size_t)kstep * 12 + cg) * 2 + kh) * 2;   // hl=0 frag index
    u16* dst = Wt2 + fi * 512 + kg * 128 + r * 8;
    uint4 vh, vl;
    vh.x = (uint)hh[0] | ((uint)hh[1] << 16); vh.y = (uint)hh[2] | ((uint)hh[3] << 16);
    vh.z = (uint)hh[4] | ((uint)hh[5] << 16); vh.w = (uint)hh[6] | ((uint)hh[7] << 16);
    vl.x = (uint)ll[0] | ((uint)ll[1] << 16); vl.y = (uint)ll[2] | ((uint)ll[3] << 16);
    vl.z = (uint)ll[4] | ((uint)ll[5] << 16); vl.w = (uint)ll[6] | ((uint)ll[7] << 16);
    *(uint4*)dst         = vh;      // hl=0
    *(uint4*)(dst + 512) = vl;      // hl=1
}

// ---------- 2. fused QKV proj: N-split blocks, W via global_load_lds, 2-phase dbuf ----------
// 512 blocks x 256 thr (4 waves). Block = (rt = row-tile, nh = cg-half). BM=32.
// Wave w: mh=w>>1 (row half), nt=w&1 (cg-triple within half). Chunk 24KB -> 2 blocks/CU.
__global__ __launch_bounds__(256, 2) void proj_kernel(
    const float* __restrict__ x, const u16* __restrict__ Wt2,
    u16* __restrict__ Qhi, u16* __restrict__ Qlo,
    u16* __restrict__ Khi, u16* __restrict__ Klo, u16* __restrict__ Vt)
{
    __shared__ u16 WB[2][12288];   // 2 x 24KB: this block's 24 frags (6 cgs)
    __shared__ u16 vs[32][72];

    const int t = threadIdx.x, w = t >> 6, lane = t & 63;
    const int lo = lane & 15, hi = lane >> 4;
    const int rt = blockIdx.x >> 1, nh = blockIdx.x & 1;
    const int row0 = rt * 32;
    const int mh = w >> 1, nt = w & 1;

    f32x4 acc[3];
#pragma unroll
    for (int i = 0; i < 3; ++i) acc[i] = (f32x4){0.f, 0.f, 0.f, 0.f};

    const float* xrow = x + (size_t)(row0 + mh * 16 + lo) * 1024 + hi * 8;

    auto stage = [&](int buf, int step) {
        // block's frags within kstep: cg in [nh*6, nh*6+6) -> u16 offset nh*12288
        const u16* src = Wt2 + (size_t)step * 24576 + (size_t)nh * 12288
                             + (size_t)(w * 6) * 512 + (size_t)lane * 8;
        u16* dst = &WB[buf][(w * 6) * 512];
#pragma unroll
        for (int i = 0; i < 6; ++i)
            gl_lds16(src + i * 512, dst + i * 512);
    };
    auto loadXf = [&](float4 (&xv)[2][2], int step) {
#pragma unroll
        for (int kh = 0; kh < 2; ++kh) {
            xv[kh][0] = *(const float4*)(xrow + step * 64 + kh * 32);
            xv[kh][1] = *(const float4*)(xrow + step * 64 + kh * 32 + 4);
        }
    };
    auto compute = [&](int buf, const float4 (&xv)[2][2]) {
        bf16x8 ah[2], al[2];
#pragma unroll
        for (int kh = 0; kh < 2; ++kh)
#pragma unroll
            for (int j = 0; j < 2; ++j)
#pragma unroll
                for (int c = 0; c < 4; ++c) {
                    const float f = (&xv[kh][j].x)[c];
                    const __bf16 h = (__bf16)f;
                    ah[kh][j * 4 + c] = h;
                    al[kh][j * 4 + c] = (__bf16)(f - (float)h);
                }
        const char* base = (const char*)&WB[buf][0];
#pragma unroll
        for (int i = 0; i < 3; ++i) {
            const int lc = nt * 3 + i;                 // local cg 0..5
#pragma unroll
            for (int kh = 0; kh < 2; ++kh) {
                const int fb = ((lc * 2 + kh) * 2) * 1024;   // bytes
                const bf16x8 wh = *(const bf16x8*)(base + fb + lane * 16);
                const bf16x8 wl = *(const bf16x8*)(base + fb + 1024 + lane * 16);
                acc[i] = MFMA16(ah[kh], wh, acc[i]);
                acc[i] = MFMA16(ah[kh], wl, acc[i]);
                acc[i] = MFMA16(al[kh], wh, acc[i]);
            }
        }
    };

    float4 xA[2][2], xB[2][2];
    stage(0, 0);
    loadXf(xA, 0);
    __syncthreads();                 // drains vmcnt(0): stage + xA complete
    int buf = 0;
    for (int step = 0; step < 16; ++step) {
        if (step < 15) { stage(buf ^ 1, step + 1); loadXf(xB, step + 1); }
        compute(buf, xA);
        __syncthreads();             // next chunk + xB landed during compute
        if (step < 15) {
#pragma unroll
            for (int kh = 0; kh < 2; ++kh) { xA[kh][0] = xB[kh][0]; xA[kh][1] = xB[kh][1]; }
        }
        buf ^= 1;
    }

    // epilogue: Q,K -> hi/lo global; V -> LDS tile then transposed global (nh=1 only)
#pragma unroll
    for (int i = 0; i < 3; ++i) {
        const int cg = nh * 6 + nt * 3 + i;
#pragma unroll
        for (int r = 0; r < 4; ++r) {
            const float v = acc[i][r];
            const int row = row0 + mh * 16 + hi * 4 + r;
            const u16 h = f2b(v);
            if (cg < 4) {
                Qhi[(size_t)row * 64 + cg * 16 + lo] = h;
                Qlo[(size_t)row * 64 + cg * 16 + lo] = f2b(v - b2f(h));
            } else if (cg < 8) {
                Khi[(size_t)row * 64 + (cg - 4) * 16 + lo] = h;
                Klo[(size_t)row * 64 + (cg - 4) * 16 + lo] = f2b(v - b2f(h));
            } else {
                vs[mh * 16 + hi * 4 + r][(cg - 8) * 16 + lo] = h;
            }
        }
    }
    __syncthreads();
    if (nh == 1) {   // Vt[b][d][tok] : 64 dims x 32 tokens, 256 threads -> 8 tokens each
        const int bb = row0 >> 11, tok0 = row0 & 2047;
        const int d = t >> 2, part = t & 3;
        u16 tmp[8];
#pragma unroll
        for (int i = 0; i < 8; ++i) tmp[i] = vs[part * 8 + i][d];
        uint4 v4;
        v4.x = (uint)tmp[0] | ((uint)tmp[1] << 16);
        v4.y = (uint)tmp[2] | ((uint)tmp[3] << 16);
        v4.z = (uint)tmp[4] | ((uint)tmp[5] << 16);
        v4.w = (uint)tmp[6] | ((uint)tmp[7] << 16);
        *(uint4*)(Vt + (size_t)bb * 131072 + (size_t)d * 2048 + tok0 + part * 8) = v4;
    }
}

// ---------- 3. flash attention: paired q-tiles, 8-wave split-K, no-max softmax ----------
// grid (64,4) x 512 thr. Block handles q-tiles 127-pi (heavy) then pi (light).
// Scores bounded (|s|<~46) -> exp() safe without max subtraction.
__global__ __launch_bounds__(512, 2) void attn_kernel(
    const u16* __restrict__ Qhi, const u16* __restrict__ Qlo,
    const u16* __restrict__ Khi, const u16* __restrict__ Klo,
    const u16* __restrict__ Vt, float* __restrict__ out)
{
    __shared__ u16 P[8][16 * 64];       // per-wave P tile, XOR-swizzled
    __shared__ float OA[8][16][64];     // per-wave partial O
    __shared__ float LS[8][16];         // per-wave partial ls

    const int pi = blockIdx.x, b = blockIdx.y;
    const int t = threadIdx.x, w = t >> 6, l = t & 63;
    const int lo = l & 15, hi = l >> 4;

    const u16* Qh = Qhi + (size_t)b * 131072;
    const u16* Ql = Qlo + (size_t)b * 131072;
    const u16* Kh = Khi + (size_t)b * 131072;
    const u16* Kl = Klo + (size_t)b * 131072;
    const u16* V  = Vt  + (size_t)b * 131072;

    u16* Pw = P[w];

#pragma unroll 1
    for (int phase = 0; phase < 2; ++phase) {
        const int p = phase ? pi : (127 - pi);
        const int q0 = p * 16;
        const int nt = (p >> 2) + 1;

        bf16x8 aqh[2], aql[2];
#pragma unroll
        for (int s = 0; s < 2; ++s) {
            aqh[s] = *(const bf16x8*)(Qh + (size_t)(q0 + lo) * 64 + s * 32 + hi * 8);
            aql[s] = *(const bf16x8*)(Ql + (size_t)(q0 + lo) * 64 + s * 32 + hi * 8);
        }

        f32x4 acc[4];
        float ls[4];
#pragma unroll
        for (int r = 0; r < 4; ++r) { acc[r] = (f32x4){0.f,0.f,0.f,0.f}; ls[r] = 0.f; }

        bf16x8 kh[4][2], kl[4][2];
        auto loadK = [&](int j0) {
#pragma unroll
            for (int kg = 0; kg < 4; ++kg)
#pragma unroll
                for (int s = 0; s < 2; ++s) {
                    const size_t off = (size_t)(j0 + kg * 16 + lo) * 64 + s * 32 + hi * 8;
                    kh[kg][s] = *(const bf16x8*)(Kh + off);
                    kl[kg][s] = *(const bf16x8*)(Kl + off);
                }
        };

        if (w < nt) loadK(w * 64);
#pragma unroll 1
        for (int j = w; j < nt; j += 8) {
            const int j0 = j * 64;
            bf16x8 bv[4][2];
#pragma unroll
            for (int dg = 0; dg < 4; ++dg)
#pragma unroll
                for (int s = 0; s < 2; ++s)
                    bv[dg][s] = *(const bf16x8*)(V + (size_t)(dg * 16 + lo) * 2048 + j0 + s * 32 + hi * 8);

            f32x4 S[4];
            const f32x4 zf = (f32x4){0.f,0.f,0.f,0.f};
#pragma unroll
            for (int kg = 0; kg < 4; ++kg) {
                f32x4 sv = zf;
                sv = MFMA16(aqh[0], kh[kg][0], sv);
                sv = MFMA16(aqh[1], kh[kg][1], sv);
                sv = MFMA16(aqh[0], kl[kg][0], sv);
                sv = MFMA16(aqh[1], kl[kg][1], sv);
                sv = MFMA16(aql[0], kh[kg][0], sv);
                sv = MFMA16(aql[1], kh[kg][1], sv);
                S[kg] = sv;
            }

            if (j + 8 < nt) loadK((j + 8) * 64);   // issue-early: flies during softmax+PV

            const bool dm = (j == nt - 1);
#pragma unroll
            for (int r = 0; r < 4; ++r) {
                const int row = q0 + hi * 4 + r;
                float sv0 = S[0][r], sv1 = S[1][r], sv2 = S[2][r], sv3 = S[3][r];
                if (dm) {
                    sv0 = (j0 +      lo > row) ? -INFINITY : sv0;
                    sv1 = (j0 + 16 + lo > row) ? -INFINITY : sv1;
                    sv2 = (j0 + 32 + lo > row) ? -INFINITY : sv2;
                    sv3 = (j0 + 48 + lo > row) ? -INFINITY : sv3;
                }
                const u16 u0 = f2b(__expf(sv0)), u1 = f2b(__expf(sv1));
                const u16 u2 = f2b(__expf(sv2)), u3 = f2b(__expf(sv3));
                float ps = b2f(u0) + b2f(u1) + b2f(u2) + b2f(u3);
#pragma unroll
                for (int msk = 8; msk; msk >>= 1) ps += __shfl_xor(ps, msk, 64);
                ls[r] += ps;
                const int rowL = hi * 4 + r;
                const int base = rowL * 64;
                const int sw = rowL & 7;
                Pw[base + (((0 + (lo >> 3)) ^ sw) << 3) + (lo & 7)] = u0;
                Pw[base + (((2 + (lo >> 3)) ^ sw) << 3) + (lo & 7)] = u1;
                Pw[base + (((4 + (lo >> 3)) ^ sw) << 3) + (lo & 7)] = u2;
                Pw[base + (((6 + (lo >> 3)) ^ sw) << 3) + (lo & 7)] = u3;
            }
            // same-wave DS producer/consumer: no barrier needed
            const bf16x8 pa0 = *(const bf16x8*)&Pw[lo * 64 + (((hi    ) ^ (lo & 7)) << 3)];
            const bf16x8 pa1 = *(const bf16x8*)&Pw[lo * 64 + (((hi + 4) ^ (lo & 7)) << 3)];
#pragma unroll
            for (int dg = 0; dg < 4; ++dg) {
                acc[dg] = MFMA16(pa0, bv[dg][0], acc[dg]);
                acc[dg] = MFMA16(pa1, bv[dg][1], acc[dg]);
            }
        }

        // ---- write per-wave partials (zeros for idle waves) ----
#pragma unroll
        for (int r = 0; r < 4; ++r) {
            if (lo == 0) LS[w][hi * 4 + r] = ls[r];
#pragma unroll
            for (int dg = 0; dg < 4; ++dg) OA[w][hi * 4 + r][dg * 16 + lo] = acc[dg][r];
        }
        __syncthreads();

        // ---- merge: plain sums over the 8 waves ----
        {
            const int row = t >> 5, c0 = (t & 31) * 2;
            float s0 = 0.f, s1 = 0.f, Lt = 0.f;
#pragma unroll
            for (int wv = 0; wv < 8; ++wv) {
                s0 += OA[wv][row][c0];
                s1 += OA[wv][row][c0 + 1];
                Lt += LS[wv][row];
            }
            const float inv = 0.125f / Lt;
            float2 o = make_float2(s0 * inv, s1 * inv);
            *(float2*)(out + ((size_t)b * 2048 + q0 + row) * 64 + c0) = o;
        }
        __syncthreads();   // protect OA/LS reuse by next phase
    }
}

extern "C" void kernel_launch(void* const* d_in, const int* in_sizes, int n_in,
                              void* d_out, int out_size, void* d_ws, size_t ws_size,
                              hipStream_t stream) {
    const float* x  = (const float*)d_in[0];
    const float* Wq = (const float*)d_in[1];
    const float* Wk = (const float*)d_in[2];
    const float* Wv = (const float*)d_in[3];
    float* outp = (float*)d_out;

    u16* Wt2 = (u16*)d_ws;               // 16*12*2*2*512 = 393216 u16 (768 KB)
    u16* Qhi = Wt2 + 393216;             // 8192*64 each
    u16* Qlo = Qhi + 524288;
    u16* Khi = Qlo + 524288;
    u16* Klo = Khi + 524288;
    u16* Vt  = Klo + 524288;             // [4][64][2048]

    wtrans_kernel<<<dim3(192), dim3(128), 0, stream>>>(Wq, Wk, Wv, Wt2);
    proj_kernel<<<dim3(512), dim3(256), 0, stream>>>(x, Wt2, Qhi, Qlo, Khi, Klo, Vt);
    attn_kernel<<<dim3(64, 4), dim3(512), 0, stream>>>(Qhi, Qlo, Khi, Klo, Vt, outp);
}

// Round 11
// 63.037 us; speedup vs baseline: 1.0745x; 1.0745x over previous
//
#include <hip/hip_runtime.h>
#include <math.h>

typedef unsigned short u16;
typedef unsigned int uint32;
typedef __attribute__((ext_vector_type(4))) float f32x4;
typedef __attribute__((ext_vector_type(4))) unsigned int u32x4;
typedef __bf16 bf16x8 __attribute__((ext_vector_type(8)));

#define MFMA16(a,b,c) __builtin_amdgcn_mfma_f32_16x16x32_bf16((a),(b),(c),0,0,0)

typedef const __attribute__((address_space(1))) unsigned GU;
typedef __attribute__((address_space(3))) unsigned LU;
__device__ __forceinline__ void gl_lds16(const void* g, void* l) {
    // dest = wave-uniform LDS base + lane*16 ; src = per-lane global address
    __builtin_amdgcn_global_load_lds((GU*)g, (LU*)l, 16, 0, 0);
}

__device__ __forceinline__ u16 f2b(float f) {
    __bf16 h = (__bf16)f;             // RNE
    return __builtin_bit_cast(u16, h);
}
__device__ __forceinline__ float b2f(u16 u) {
    unsigned v = (unsigned)u << 16;
    return __builtin_bit_cast(float, v);
}

// pinned-count asm primitives
__device__ __forceinline__ void agload4(f32x4& d, const float* p) {
    asm volatile("global_load_dwordx4 %0, %1, off" : "=&v"(d) : "v"(p) : "memory");
}
__device__ __forceinline__ void dsr(bf16x8& d, uint32 a) {
    u32x4 tmp;
    asm volatile("ds_read_b128 %0, %1" : "=&v"(tmp) : "v"(a) : "memory");
    d = __builtin_bit_cast(bf16x8, tmp);
}
#define WAITVM_I(n) asm volatile("s_waitcnt vmcnt(" #n ")" ::: "memory")
#define WAITVM(n) WAITVM_I(n)

// ---------- 1. wtrans: W[1024][64] f32 x3 -> fragment-native Wt2 ----------
// Wt2 u16 [kstep=16][cg=12][kh=2][hl=2][kg=4][r=16][e=8]  (1KB frags, 768KB total)
__global__ __launch_bounds__(128) void wtrans_kernel(
    const float* __restrict__ Wq, const float* __restrict__ Wk,
    const float* __restrict__ Wv, u16* __restrict__ Wt2)
{
    const int n = blockIdx.x;                         // 0..191
    const float* W = (n < 64) ? Wq : ((n < 128) ? Wk : Wv);
    const int nc = n & 63, cg = n >> 4, r = n & 15;
    const int t = threadIdx.x;                        // 0..127
    const int k0 = t * 8;
    const int kstep = k0 >> 6, kh = (k0 >> 5) & 1, kg = (k0 >> 3) & 3;
    u16 hh[8], ll[8];
#pragma unroll
    for (int i = 0; i < 8; ++i) {
        const float a = W[(size_t)(k0 + i) * 64 + nc];
        hh[i] = f2b(a);
        ll[i] = f2b(a - b2f(hh[i]));
    }
    const size_t fi = (((size_t)kstep * 12 + cg) * 2 + kh) * 2;   // hl=0 frag index
    u16* dst = Wt2 + fi * 512 + kg * 128 + r * 8;
    uint4 vh, vl;
    vh.x = (uint)hh[0] | ((uint)hh[1] << 16); vh.y = (uint)hh[2] | ((uint)hh[3] << 16);
    vh.z = (uint)hh[4] | ((uint)hh[5] << 16); vh.w = (uint)hh[6] | ((uint)hh[7] << 16);
    vl.x = (uint)ll[0] | ((uint)ll[1] << 16); vl.y = (uint)ll[2] | ((uint)ll[3] << 16);
    vl.z = (uint)ll[4] | ((uint)ll[5] << 16); vl.w = (uint)ll[6] | ((uint)ll[7] << 16);
    *(uint4*)dst         = vh;      // hl=0
    *(uint4*)(dst + 512) = vl;      // hl=1
}

// helpers for proj pipeline (all counts exact: 6 gl_lds per stage, 8 asm loads per X issue)
__device__ __forceinline__ void stage6(const u16* __restrict__ Wt2,
                                       u16 (&WB)[4][3][6][512],
                                       int w, int nq, int reg, int step, int kh, int lane) {
#pragma unroll
    for (int i = 0; i < 3; ++i)
#pragma unroll
        for (int hl = 0; hl < 2; ++hl) {
            const int fi = ((step * 12 + nq * 3 + i) * 2 + kh) * 2 + hl;
            gl_lds16(Wt2 + (size_t)fi * 512 + lane * 8, &WB[w][reg][i * 2 + hl][0]);
        }
}
__device__ __forceinline__ void issue8(f32x4 (&xs)[8], const float* r0, const float* r1, int step) {
#pragma unroll
    for (int kh = 0; kh < 2; ++kh)
#pragma unroll
        for (int j = 0; j < 2; ++j) {
            agload4(xs[0 * 4 + kh * 2 + j], r0 + step * 64 + kh * 32 + j * 4);
            agload4(xs[1 * 4 + kh * 2 + j], r1 + step * 64 + kh * 32 + j * 4);
        }
}
__device__ __forceinline__ void conv8(bf16x8& ah, bf16x8& al, f32x4 a, f32x4 b) {
#pragma unroll
    for (int e = 0; e < 4; ++e) {
        { float v = a[e]; __bf16 hb = (__bf16)v; ah[e] = hb; al[e] = (__bf16)(v - (float)hb); }
        { float v = b[e]; __bf16 hb = (__bf16)v; ah[4 + e] = hb; al[4 + e] = (__bf16)(v - (float)hb); }
    }
}

// one software-pipeline half-step (fully static); WC_ = exact vmcnt to keep in flight
#define PROJ_HALF(H_, WC_)                                                          \
    do {                                                                            \
        if ((H_) + 2 <= 31) {                                                       \
            stage6(Wt2, WB, w, nq, ((H_) + 2) % 3, ((H_) + 2) >> 1, ((H_) + 2) & 1, lane); \
        }                                                                           \
        if ((((H_) & 1) == 0) && ((H_) >> 1) + 2 <= 15) {                           \
            issue8(xr[(((H_) >> 1) + 2) % 3], xrow0, xrow1, ((H_) >> 1) + 2);       \
        }                                                                           \
        WAITVM(WC_);                                                                \
        __builtin_amdgcn_sched_barrier(0);                                          \
        bf16x8 wh0, wl0, wh1, wl1, wh2, wl2;                                        \
        dsr(wh0, dsa + (uint32)((((H_) % 3) * 6 + 0) * 1024));                      \
        dsr(wl0, dsa + (uint32)((((H_) % 3) * 6 + 1) * 1024));                      \
        dsr(wh1, dsa + (uint32)((((H_) % 3) * 6 + 2) * 1024));                      \
        dsr(wl1, dsa + (uint32)((((H_) % 3) * 6 + 3) * 1024));                      \
        dsr(wh2, dsa + (uint32)((((H_) % 3) * 6 + 4) * 1024));                      \
        dsr(wl2, dsa + (uint32)((((H_) % 3) * 6 + 5) * 1024));                      \
        asm volatile("s_waitcnt lgkmcnt(0)" ::: "memory");                          \
        __builtin_amdgcn_sched_barrier(0);                                          \
        _Pragma("unroll")                                                           \
        for (int rg = 0; rg < 2; ++rg) {                                            \
            bf16x8 ah, al;                                                          \
            conv8(ah, al, xr[((H_) >> 1) % 3][rg * 4 + ((H_) & 1) * 2 + 0],         \
                          xr[((H_) >> 1) % 3][rg * 4 + ((H_) & 1) * 2 + 1]);        \
            acc[rg][0] = MFMA16(ah, wh0, acc[rg][0]);                               \
            acc[rg][0] = MFMA16(ah, wl0, acc[rg][0]);                               \
            acc[rg][0] = MFMA16(al, wh0, acc[rg][0]);                               \
            acc[rg][1] = MFMA16(ah, wh1, acc[rg][1]);                               \
            acc[rg][1] = MFMA16(ah, wl1, acc[rg][1]);                               \
            acc[rg][1] = MFMA16(al, wh1, acc[rg][1]);                               \
            acc[rg][2] = MFMA16(ah, wh2, acc[rg][2]);                               \
            acc[rg][2] = MFMA16(ah, wl2, acc[rg][2]);                               \
            acc[rg][2] = MFMA16(al, wh2, acc[rg][2]);                               \
        }                                                                           \
    } while (0)

// ---------- 2. fused QKV proj: barrier-free wave-private counted-vmcnt pipeline ----------
// 256 blocks x 256 thr (4 waves). Wave w = cg-triple nq=w over 32 rows (full K).
// 3-region wave-private W LDS (gl_lds, 2-half lead); x via asm loads (2-step lead).
__global__ __launch_bounds__(256) void proj_kernel(
    const float* __restrict__ x, const u16* __restrict__ Wt2,
    u16* __restrict__ Qhi, u16* __restrict__ Qlo,
    u16* __restrict__ Khi, u16* __restrict__ Klo, u16* __restrict__ Vt)
{
    __shared__ u16 WB[4][3][6][512];   // 72 KB: [wave][region][frag cg*2+hl][1KB]
    __shared__ u16 vs[32][72];

    const int t = threadIdx.x, w = t >> 6, lane = t & 63;
    const int lo = lane & 15, hi = lane >> 4;
    const int nq = w;
    const int row0 = blockIdx.x * 32;

    f32x4 acc[2][3];
#pragma unroll
    for (int rg = 0; rg < 2; ++rg)
#pragma unroll
        for (int i = 0; i < 3; ++i) acc[rg][i] = (f32x4){0.f, 0.f, 0.f, 0.f};

    const float* xrow0 = x + (size_t)(row0 + lo) * 1024 + hi * 8;
    const float* xrow1 = x + (size_t)(row0 + 16 + lo) * 1024 + hi * 8;
    const uint32 wbase = (uint32)(size_t)(LU*)(&WB[w][0][0][0]);
    const uint32 dsa = wbase + (uint32)lane * 16u;

    f32x4 xr[3][8];

    // prologue — issue order pinned by asm memory clobbers: L0, X0, L1, X1
    stage6(Wt2, WB, w, nq, 0, 0, 0, lane);
    issue8(xr[0], xrow0, xrow1, 0);
    stage6(Wt2, WB, w, nq, 1, 0, 1, lane);
    issue8(xr[1], xrow0, xrow1, 1);

    PROJ_HALF(0, 28);  PROJ_HALF(1, 20);  PROJ_HALF(2, 28);  PROJ_HALF(3, 20);
    PROJ_HALF(4, 28);  PROJ_HALF(5, 20);  PROJ_HALF(6, 28);  PROJ_HALF(7, 20);
    PROJ_HALF(8, 28);  PROJ_HALF(9, 20);  PROJ_HALF(10, 28); PROJ_HALF(11, 20);
    PROJ_HALF(12, 28); PROJ_HALF(13, 20); PROJ_HALF(14, 28); PROJ_HALF(15, 20);
    PROJ_HALF(16, 28); PROJ_HALF(17, 20); PROJ_HALF(18, 28); PROJ_HALF(19, 20);
    PROJ_HALF(20, 28); PROJ_HALF(21, 20); PROJ_HALF(22, 28); PROJ_HALF(23, 20);
    PROJ_HALF(24, 28); PROJ_HALF(25, 20); PROJ_HALF(26, 28); PROJ_HALF(27, 20);
    PROJ_HALF(28, 20); PROJ_HALF(29, 12); PROJ_HALF(30, 6);  PROJ_HALF(31, 0);

    // epilogue: Q,K -> hi/lo global; V -> LDS tile then transposed global
#pragma unroll
    for (int rg = 0; rg < 2; ++rg)
#pragma unroll
    for (int i = 0; i < 3; ++i) {
        const int cg = nq * 3 + i;
#pragma unroll
        for (int r = 0; r < 4; ++r) {
            const float v = acc[rg][i][r];
            const int row = row0 + rg * 16 + hi * 4 + r;
            const u16 h = f2b(v);
            if (cg < 4) {
                Qhi[(size_t)row * 64 + cg * 16 + lo] = h;
                Qlo[(size_t)row * 64 + cg * 16 + lo] = f2b(v - b2f(h));
            } else if (cg < 8) {
                Khi[(size_t)row * 64 + (cg - 4) * 16 + lo] = h;
                Klo[(size_t)row * 64 + (cg - 4) * 16 + lo] = f2b(v - b2f(h));
            } else {
                vs[rg * 16 + hi * 4 + r][(cg - 8) * 16 + lo] = h;
            }
        }
    }
    __syncthreads();
    {   // Vt[b][d][tok] : 64 dims x 32 tokens, 256 threads -> 8 tokens each
        const int bb = row0 >> 11, tok0 = row0 & 2047;
        const int d = t >> 2, part = t & 3;
        u16 tmp[8];
#pragma unroll
        for (int i = 0; i < 8; ++i) tmp[i] = vs[part * 8 + i][d];
        uint4 v4;
        v4.x = (uint)tmp[0] | ((uint)tmp[1] << 16);
        v4.y = (uint)tmp[2] | ((uint)tmp[3] << 16);
        v4.z = (uint)tmp[4] | ((uint)tmp[5] << 16);
        v4.w = (uint)tmp[6] | ((uint)tmp[7] << 16);
        *(uint4*)(Vt + (size_t)bb * 131072 + (size_t)d * 2048 + tok0 + part * 8) = v4;
    }
}

// ---------- 3. flash attention: paired q-tiles, 8-wave split-K, no-max softmax ----------
// grid (64,4) x 512 thr. Block handles q-tiles 127-pi (heavy) then pi (light).
// Scores bounded (|s|<~46) -> exp() safe without max subtraction.
__global__ __launch_bounds__(512, 2) void attn_kernel(
    const u16* __restrict__ Qhi, const u16* __restrict__ Qlo,
    const u16* __restrict__ Khi, const u16* __restrict__ Klo,
    const u16* __restrict__ Vt, float* __restrict__ out)
{
    __shared__ u16 P[8][16 * 64];       // per-wave P tile, XOR-swizzled
    __shared__ float OA[8][16][64];     // per-wave partial O
    __shared__ float LS[8][16];         // per-wave partial ls

    const int pi = blockIdx.x, b = blockIdx.y;
    const int t = threadIdx.x, w = t >> 6, l = t & 63;
    const int lo = l & 15, hi = l >> 4;

    const u16* Qh = Qhi + (size_t)b * 131072;
    const u16* Ql = Qlo + (size_t)b * 131072;
    const u16* Kh = Khi + (size_t)b * 131072;
    const u16* Kl = Klo + (size_t)b * 131072;
    const u16* V  = Vt  + (size_t)b * 131072;

    u16* Pw = P[w];

#pragma unroll 1
    for (int phase = 0; phase < 2; ++phase) {
        const int p = phase ? pi : (127 - pi);
        const int q0 = p * 16;
        const int nt = (p >> 2) + 1;

        bf16x8 aqh[2], aql[2];
#pragma unroll
        for (int s = 0; s < 2; ++s) {
            aqh[s] = *(const bf16x8*)(Qh + (size_t)(q0 + lo) * 64 + s * 32 + hi * 8);
            aql[s] = *(const bf16x8*)(Ql + (size_t)(q0 + lo) * 64 + s * 32 + hi * 8);
        }

        f32x4 acc[4];
        float ls[4];
#pragma unroll
        for (int r = 0; r < 4; ++r) { acc[r] = (f32x4){0.f,0.f,0.f,0.f}; ls[r] = 0.f; }

        bf16x8 kh[4][2], kl[4][2];
        auto loadK = [&](int j0) {
#pragma unroll
            for (int kg = 0; kg < 4; ++kg)
#pragma unroll
                for (int s = 0; s < 2; ++s) {
                    const size_t off = (size_t)(j0 + kg * 16 + lo) * 64 + s * 32 + hi * 8;
                    kh[kg][s] = *(const bf16x8*)(Kh + off);
                    kl[kg][s] = *(const bf16x8*)(Kl + off);
                }
        };

        if (w < nt) loadK(w * 64);
#pragma unroll 1
        for (int j = w; j < nt; j += 8) {
            const int j0 = j * 64;
            bf16x8 bv[4][2];
#pragma unroll
            for (int dg = 0; dg < 4; ++dg)
#pragma unroll
                for (int s = 0; s < 2; ++s)
                    bv[dg][s] = *(const bf16x8*)(V + (size_t)(dg * 16 + lo) * 2048 + j0 + s * 32 + hi * 8);

            f32x4 S[4];
            const f32x4 zf = (f32x4){0.f,0.f,0.f,0.f};
#pragma unroll
            for (int kg = 0; kg < 4; ++kg) {
                f32x4 sv = zf;
                sv = MFMA16(aqh[0], kh[kg][0], sv);
                sv = MFMA16(aqh[1], kh[kg][1], sv);
                sv = MFMA16(aqh[0], kl[kg][0], sv);
                sv = MFMA16(aqh[1], kl[kg][1], sv);
                sv = MFMA16(aql[0], kh[kg][0], sv);
                sv = MFMA16(aql[1], kh[kg][1], sv);
                S[kg] = sv;
            }

            if (j + 8 < nt) loadK((j + 8) * 64);   // issue-early: flies during softmax+PV

            const bool dm = (j == nt - 1);
#pragma unroll
            for (int r = 0; r < 4; ++r) {
                const int row = q0 + hi * 4 + r;
                float sv0 = S[0][r], sv1 = S[1][r], sv2 = S[2][r], sv3 = S[3][r];
                if (dm) {
                    sv0 = (j0 +      lo > row) ? -INFINITY : sv0;
                    sv1 = (j0 + 16 + lo > row) ? -INFINITY : sv1;
                    sv2 = (j0 + 32 + lo > row) ? -INFINITY : sv2;
                    sv3 = (j0 + 48 + lo > row) ? -INFINITY : sv3;
                }
                const u16 u0 = f2b(__expf(sv0)), u1 = f2b(__expf(sv1));
                const u16 u2 = f2b(__expf(sv2)), u3 = f2b(__expf(sv3));
                float ps = b2f(u0) + b2f(u1) + b2f(u2) + b2f(u3);
#pragma unroll
                for (int msk = 8; msk; msk >>= 1) ps += __shfl_xor(ps, msk, 64);
                ls[r] += ps;
                const int rowL = hi * 4 + r;
                const int base = rowL * 64;
                const int sw = rowL & 7;
                Pw[base + (((0 + (lo >> 3)) ^ sw) << 3) + (lo & 7)] = u0;
                Pw[base + (((2 + (lo >> 3)) ^ sw) << 3) + (lo & 7)] = u1;
                Pw[base + (((4 + (lo >> 3)) ^ sw) << 3) + (lo & 7)] = u2;
                Pw[base + (((6 + (lo >> 3)) ^ sw) << 3) + (lo & 7)] = u3;
            }
            // same-wave DS producer/consumer: no barrier needed
            const bf16x8 pa0 = *(const bf16x8*)&Pw[lo * 64 + (((hi    ) ^ (lo & 7)) << 3)];
            const bf16x8 pa1 = *(const bf16x8*)&Pw[lo * 64 + (((hi + 4) ^ (lo & 7)) << 3)];
#pragma unroll
            for (int dg = 0; dg < 4; ++dg) {
                acc[dg] = MFMA16(pa0, bv[dg][0], acc[dg]);
                acc[dg] = MFMA16(pa1, bv[dg][1], acc[dg]);
            }
        }

        // ---- write per-wave partials (zeros for idle waves) ----
#pragma unroll
        for (int r = 0; r < 4; ++r) {
            if (lo == 0) LS[w][hi * 4 + r] = ls[r];
#pragma unroll
            for (int dg = 0; dg < 4; ++dg) OA[w][hi * 4 + r][dg * 16 + lo] = acc[dg][r];
        }
        __syncthreads();

        // ---- merge: plain sums over the 8 waves ----
        {
            const int row = t >> 5, c0 = (t & 31) * 2;
            float s0 = 0.f, s1 = 0.f, Lt = 0.f;
#pragma unroll
            for (int wv = 0; wv < 8; ++wv) {
                s0 += OA[wv][row][c0];
                s1 += OA[wv][row][c0 + 1];
                Lt += LS[wv][row];
            }
            const float inv = 0.125f / Lt;
            float2 o = make_float2(s0 * inv, s1 * inv);
            *(float2*)(out + ((size_t)b * 2048 + q0 + row) * 64 + c0) = o;
        }
        __syncthreads();   // protect OA/LS reuse by next phase
    }
}

extern "C" void kernel_launch(void* const* d_in, const int* in_sizes, int n_in,
                              void* d_out, int out_size, void* d_ws, size_t ws_size,
                              hipStream_t stream) {
    const float* x  = (const float*)d_in[0];
    const float* Wq = (const float*)d_in[1];
    const float* Wk = (const float*)d_in[2];
    const float* Wv = (const float*)d_in[3];
    float* outp = (float*)d_out;

    u16* Wt2 = (u16*)d_ws;               // 16*12*2*2*512 = 393216 u16 (768 KB)
    u16* Qhi = Wt2 + 393216;             // 8192*64 each
    u16* Qlo = Qhi + 524288;
    u16* Khi = Qlo + 524288;
    u16* Klo = Khi + 524288;
    u16* Vt  = Klo + 524288;             // [4][64][2048]

    wtrans_kernel<<<dim3(192), dim3(128), 0, stream>>>(Wq, Wk, Wv, Wt2);
    proj_kernel<<<dim3(256), dim3(256), 0, stream>>>(x, Wt2, Qhi, Qlo, Khi, Klo, Vt);
    attn_kernel<<<dim3(64, 4), dim3(512), 0, stream>>>(Qhi, Qlo, Khi, Klo, Vt, outp);
}